// Round 3
// baseline (365.821 us; speedup 1.0000x reference)
//
#include <hip/hip_runtime.h>

// result = 0.25*sum(M) - 0.5*[ sum_{i<j} M_ij s_i s_j + sum_i M_ii s_i ]
//
// R6: grid-stride sweep. R3/R5 (block-owns-contiguous-rows) plateaued at
// ~2.7-2.9 TB/s read BW despite ideal FETCH_SIZE, no spill, 16 waves/CU and
// 8 loads in flight per wave. Remaining structural difference vs the 6.6 TB/s
// fill/copy kernels: their instantaneous chip-wide footprint is one
// CONTIGUOUS window sweeping memory (grid-stride), ours was 1024 streams
// strided by 256 KB (power-of-2 sparse channel pattern). R6 makes the whole
// chip sweep a contiguous ~8 MB band: each thread owns a FIXED float4 column
// chunk v (state value sj in one register, loaded once) and walks 32 rows
// spaced 256 apart. row = row0+256*it is block-uniform -> scalar state load;
// VGPR ~50 -> 32 waves/CU, GRID=2048 = 8 blocks/CU, one generation.

static constexpr int N_DIM  = 8192;
static constexpr int VPR    = N_DIM / 4;    // 2048 float4 per row
static constexpr int BLOCK  = 256;
static constexpr int GRID   = 2048;         // 8 blocks/CU, all resident
static constexpr int ITERS  = N_DIM / 256;  // 32 rows per thread, 256 apart
static constexpr int FBLOCK = 1024;

__global__ __launch_bounds__(BLOCK) void ising_sweep_kernel(
    const float4* __restrict__ mtx4,
    const float*  __restrict__ state,
    float*        __restrict__ partial)
{
    const int tid  = threadIdx.x;
    const int row0 = blockIdx.x >> 3;                 // 0..255, block-uniform
    const int v    = ((blockIdx.x & 7) << 8) + tid;   // 0..2047, fixed per thread
    const float4 sj = ((const float4*)state)[v];      // loaded ONCE
    const float4* __restrict__ colp = mtx4 + v;

    float acc0 = 0.0f, acc1 = 0.0f;                   // 2 chains: shorter dep path
#pragma unroll 8
    for (int it = 0; it < ITERS; ++it) {
        const int   row = row0 + (it << 8);           // block-uniform
        const int   d   = row >> 2;
        const float p   = -0.5f * state[row];         // scalar (s_load) path
        const float4 mm = colp[(size_t)row * VPR];    // 1 KB/wave-instr, coalesced

        const float accA = (mm.x + mm.y) + (mm.z + mm.w);

        const bool gt = (v > d);                      // per-lane predication
        float wx = gt ? sj.x : 0.0f;
        float wy = gt ? sj.y : 0.0f;
        float wz = gt ? sj.z : 0.0f;
        float ww = gt ? sj.w : 0.0f;
        if (v == d) {                                 // execz-skipped for ~all waves
            const int j0 = v << 2;
            wx = (j0 + 0 > row) ? sj.x : ((j0 + 0 == row) ? 1.0f : 0.0f);
            wy = (j0 + 1 > row) ? sj.y : ((j0 + 1 == row) ? 1.0f : 0.0f);
            wz = (j0 + 2 > row) ? sj.z : ((j0 + 2 == row) ? 1.0f : 0.0f);
            ww = (j0 + 3 > row) ? sj.w : ((j0 + 3 == row) ? 1.0f : 0.0f);
        }
        float q = mm.x * wx;
        q = fmaf(mm.y, wy, q);
        q = fmaf(mm.z, wz, q);
        q = fmaf(mm.w, ww, q);

        if (it & 1) acc1 = fmaf(0.25f, accA, fmaf(p, q, acc1));
        else        acc0 = fmaf(0.25f, accA, fmaf(p, q, acc0));
    }
    float acc = acc0 + acc1;

    // One reduction per block.
    for (int off = 32; off > 0; off >>= 1)
        acc += __shfl_down(acc, off, 64);

    __shared__ float lds[BLOCK / 64];
    const int lane = tid & 63;
    const int wave = tid >> 6;
    if (lane == 0) lds[wave] = acc;
    __syncthreads();
    if (tid == 0)
        partial[blockIdx.x] = (lds[0] + lds[1]) + (lds[2] + lds[3]);
}

__global__ __launch_bounds__(FBLOCK) void ising_final_kernel(
    const float* __restrict__ partial,
    float*       __restrict__ out)
{
    float acc = partial[threadIdx.x] + partial[threadIdx.x + FBLOCK]; // GRID=2048

    for (int off = 32; off > 0; off >>= 1)
        acc += __shfl_down(acc, off, 64);

    __shared__ float lds[FBLOCK / 64];
    const int lane = threadIdx.x & 63;
    const int wave = threadIdx.x >> 6;
    if (lane == 0) lds[wave] = acc;
    __syncthreads();
    if (threadIdx.x == 0) {
        float sum = 0.0f;
#pragma unroll
        for (int w = 0; w < FBLOCK / 64; ++w) sum += lds[w];
        out[0] = sum;
    }
}

extern "C" void kernel_launch(void* const* d_in, const int* in_sizes, int n_in,
                              void* d_out, int out_size, void* d_ws, size_t ws_size,
                              hipStream_t stream) {
    const float* mtx   = (const float*)d_in[0];   // [8192*8192] fp32
    const float* state = (const float*)d_in[1];   // [8192] fp32
    float* out     = (float*)d_out;
    float* partial = (float*)d_ws;                // 2048 floats, fully overwritten

    ising_sweep_kernel<<<GRID, BLOCK, 0, stream>>>((const float4*)mtx, state, partial);
    ising_final_kernel<<<1, FBLOCK, 0, stream>>>(partial, out);
}

// Round 4
// 330.463 us; speedup vs baseline: 1.1070x; 1.1070x over previous
//
#include <hip/hip_runtime.h>

// result = 0.25*sum(M) - 0.5*[ sum_{i<j} M_ij s_i s_j + sum_i M_ii s_i ]
//
// R7 = R3 (best measured structure: block-per-row, 16 hoisted loads) with
// ONE change: matrix loads are NON-TEMPORAL. Theory: the harness's 1 GiB
// workspace fill runs right before us and leaves the 256 MiB write-back L3
// full of dirty lines; our 268 MB read-miss stream evicts them, dragging
// ~190 MB of HBM writebacks behind our reads (seen as WRITE_SIZE=189 MB on
// the R4 row kernel). nt-policy reads don't allocate/displace in L3 ->
// (1) row kernel sheds the inherited writebacks, (2) dirty workspace lines
// survive until the next fill overwrites them in-cache, shaving fill
// traffic too. State loads stay cacheable (32 KiB, reused by all blocks).

static constexpr int N_DIM = 8192;
static constexpr int VPR   = N_DIM / 4;    // 2048 float4 per row
static constexpr int BLOCK = 256;
static constexpr int ITERS = VPR / BLOCK;  // 8 float4 per thread
static constexpr int FBLOCK = 1024;

__device__ __forceinline__ float4 ntload4(const float4* p) {
    typedef float f32x4 __attribute__((ext_vector_type(4)));
    const f32x4 v = __builtin_nontemporal_load((const f32x4*)p);
    return make_float4(v.x, v.y, v.z, v.w);
}

__global__ __launch_bounds__(BLOCK) void ising_row_kernel(
    const float4* __restrict__ mtx4,
    const float*  __restrict__ state,
    float*        __restrict__ partial)
{
    const int   row = blockIdx.x;
    const int   d   = row >> 2;            // diagonal's vec4 index (block-scalar)
    const float p   = -0.5f * state[row];
    const float4* __restrict__ rowp = mtx4 + (size_t)row * VPR;
    const float4* __restrict__ s4   = (const float4*)state;

    // Hoist all loads before any branch: 16 independent dwordx4 in flight.
    float4 m[ITERS];
    float4 s[ITERS];
#pragma unroll
    for (int k = 0; k < ITERS; ++k)
        m[k] = ntload4(rowp + threadIdx.x + (k << 8));   // nt: no L3 displacement
#pragma unroll
    for (int k = 0; k < ITERS; ++k)
        s[k] = s4[threadIdx.x + (k << 8)];     // 32 KiB total, cacheable (reused)

    float accA  = 0.0f;                    // sum of all m (0.25*sum(M) term)
    float accQ0 = 0.0f, accQ1 = 0.0f;      // masked dot (scaled by p at the end)
#pragma unroll
    for (int k = 0; k < ITERS; ++k) {
        const int    v  = threadIdx.x + (k << 8);
        const float4 mm = m[k];
        const float4 sj = s[k];
        accA += (mm.x + mm.y) + (mm.z + mm.w);
        if (v > d) {                       // wave-uniform except 1 wave/block
            accQ0 = fmaf(mm.x, sj.x, accQ0);
            accQ1 = fmaf(mm.y, sj.y, accQ1);
            accQ0 = fmaf(mm.z, sj.z, accQ0);
            accQ1 = fmaf(mm.w, sj.w, accQ1);
        } else if (v == d) {               // exactly one thread per block
            const int j0 = v << 2;
            float w;
            w = (j0 + 0 > row) ? sj.x : ((j0 + 0 == row) ? 1.0f : 0.0f);
            accQ0 = fmaf(mm.x, w, accQ0);
            w = (j0 + 1 > row) ? sj.y : ((j0 + 1 == row) ? 1.0f : 0.0f);
            accQ1 = fmaf(mm.y, w, accQ1);
            w = (j0 + 2 > row) ? sj.z : ((j0 + 2 == row) ? 1.0f : 0.0f);
            accQ0 = fmaf(mm.z, w, accQ0);
            w = (j0 + 3 > row) ? sj.w : ((j0 + 3 == row) ? 1.0f : 0.0f);
            accQ1 = fmaf(mm.w, w, accQ1);
        }
    }

    float acc = fmaf(0.25f, accA, p * (accQ0 + accQ1));

    // wave-64 shuffle reduction, then 4-entry LDS combine
    for (int off = 32; off > 0; off >>= 1)
        acc += __shfl_down(acc, off, 64);

    __shared__ float lds[BLOCK / 64];
    const int lane = threadIdx.x & 63;
    const int wave = threadIdx.x >> 6;
    if (lane == 0) lds[wave] = acc;
    __syncthreads();
    if (threadIdx.x == 0)
        partial[blockIdx.x] = (lds[0] + lds[1]) + (lds[2] + lds[3]);
}

__global__ __launch_bounds__(FBLOCK) void ising_final_kernel(
    const float* __restrict__ partial,
    float*       __restrict__ out)
{
    float acc = 0.0f;
#pragma unroll
    for (int k = 0; k < N_DIM / FBLOCK; ++k)
        acc += partial[threadIdx.x + k * FBLOCK];

    for (int off = 32; off > 0; off >>= 1)
        acc += __shfl_down(acc, off, 64);

    __shared__ float lds[FBLOCK / 64];
    const int lane = threadIdx.x & 63;
    const int wave = threadIdx.x >> 6;
    if (lane == 0) lds[wave] = acc;
    __syncthreads();
    if (threadIdx.x == 0) {
        float sum = 0.0f;
#pragma unroll
        for (int w = 0; w < FBLOCK / 64; ++w) sum += lds[w];
        out[0] = sum;
    }
}

extern "C" void kernel_launch(void* const* d_in, const int* in_sizes, int n_in,
                              void* d_out, int out_size, void* d_ws, size_t ws_size,
                              hipStream_t stream) {
    const float* mtx   = (const float*)d_in[0];   // [8192*8192] fp32
    const float* state = (const float*)d_in[1];   // [8192] fp32
    float* out     = (float*)d_out;
    float* partial = (float*)d_ws;                // 8192 floats, fully overwritten

    ising_row_kernel<<<N_DIM, BLOCK, 0, stream>>>((const float4*)mtx, state, partial);
    ising_final_kernel<<<1, FBLOCK, 0, stream>>>(partial, out);
}